// Round 3
// baseline (590.142 us; speedup 1.0000x reference)
//
#include <hip/hip_runtime.h>
#include <math.h>

// ---------------------------------------------------------------------------
// WaveRNN fused, wave-per-item, LDS-aliased: conv1(1->4,k31,s4,p15) -> relu ->
// conv2(4->8,k15,s4,p7) -> relu -> conv3(8->16,k7,s4,p3) -> relu -> mean ->
// GRU (H=32) -> proj.  64-thread (1-wave) blocks, one batch item each.
//
// LDS per block = 12544 B (y1s 2048f | U 1056f | hs 32f) -> ~12-13 blocks/CU
// (vs 17920 B / 8 blocks in round 2).  U is time-multiplexed:
//   phase conv1 : xbuf  (pad16 | 1016 staged floats | pad16)  = 1048f
//   phase conv2+: y2s   (8 ch x [pad3 | 125 | pad4])          = 1056f
// GRU ctx / gate exchange live in registers + __shfl_xor (no LDS, no barrier).
// Conv weight indices are all compile-time -> scalar s_load operands (K$-hot).
// ---------------------------------------------------------------------------

__device__ __forceinline__ void conv1_pos(const float* __restrict__ xbuf,
                                          float* __restrict__ y1s,
                                          const float* __restrict__ w1,
                                          const float* __restrict__ b1,
                                          int p, int q0)
{
    const float4* src = (const float4*)xbuf;
    float xin[32];
#pragma unroll
    for (int j = 0; j < 8; ++j) {
        float4 q = src[q0 + j];
        xin[4 * j + 0] = q.x; xin[4 * j + 1] = q.y;
        xin[4 * j + 2] = q.z; xin[4 * j + 3] = q.w;
    }
    float a0 = b1[0], a1 = b1[1], a2 = b1[2], a3 = b1[3];
#pragma unroll
    for (int k = 0; k < 31; ++k) {
        float xv = xin[k + 1];
        a0 += xv * w1[k];
        a1 += xv * w1[31 + k];
        a2 += xv * w1[62 + k];
        a3 += xv * w1[93 + k];
    }
    y1s[7 + p]        = fmaxf(a0, 0.0f);
    y1s[512 + 7 + p]  = fmaxf(a1, 0.0f);
    y1s[1024 + 7 + p] = fmaxf(a2, 0.0f);
    y1s[1536 + 7 + p] = fmaxf(a3, 0.0f);
}

__global__ void __launch_bounds__(64, 3)
wavernn_fused(const float* __restrict__ past,      // (B,2000)
              const float* __restrict__ velocity,  // (B,)
              const float* __restrict__ log_pitch, // (B,)
              const float* __restrict__ time_in,   // (B,)
              const float* __restrict__ hidden,    // (B,32)
              const float* __restrict__ w1, const float* __restrict__ b1,
              const float* __restrict__ w2, const float* __restrict__ b2,
              const float* __restrict__ w3, const float* __restrict__ b3,
              const float* __restrict__ w_ih, const float* __restrict__ w_hh,
              const float* __restrict__ b_ih, const float* __restrict__ b_hh,
              const float* __restrict__ w_proj, const float* __restrict__ b_proj,
              float* __restrict__ out, int B)
{
    __shared__ __align__(16) float smem[3136];
    float* const y1s  = smem;          // 2048 floats
    float* const U    = smem + 2048;   // 1056 floats (xbuf / y2s)
    float* const hs   = smem + 3104;   // 32 floats

    float* const xbuf = U;
    float* const y2s  = U;
    float4* const xb4 = (float4*)U;

    const int t = threadIdx.x;       // 0..63, single wave
    const int b = blockIdx.x;

    const float4* row4 = (const float4*)(past + (size_t)b * 2000);

    // wave-uniform scalars (s_load path), hoisted for latency
    const float vel = velocity[b];
    const float lpi = log_pitch[b];
    const float tmi = time_in[b];

    // ---------------- pads + hidden stage + chunk0 stage + chunk1 prefetch --
    if (t < 16) { xbuf[t] = 0.0f; xbuf[1032 + t] = 0.0f; }
    if (t < 48) { int c = t / 12, k = t % 12;
                  y1s[c * 512 + (k < 7 ? k : 500 + k)] = 0.0f; }
    if (t < 32) hs[t] = hidden[(size_t)b * 32 + t];

    float4 pre[4];
#pragma unroll
    for (int j = 0; j < 4; ++j) {
        int i = t + 64 * j;
        if (i < 254) {
            xb4[4 + i] = row4[i];        // chunk0: x[0..1015] at xbuf[16+..]
            pre[j]     = row4[246 + i];  // chunk1: x[984..1999] to regs
        }
    }
    __syncthreads();

    // ---------------- conv1 chunk 0: positions 0..249 ----------------
#pragma unroll
    for (int j = 0; j < 4; ++j) {
        int p = t + 64 * j;
        if (p < 250) conv1_pos(xbuf, y1s, w1, b1, p, p);
    }
    __syncthreads();                     // WAR: all reads of xbuf done

    // ---------------- commit chunk 1 from registers ----------------
#pragma unroll
    for (int j = 0; j < 4; ++j) {
        int i = t + 64 * j;
        if (i < 254) xb4[4 + i] = pre[j];  // xbuf[16+4i] <- x[984+4i]
    }
    __syncthreads();

    // ---------------- conv1 chunk 1: positions 250..499 ----------------
#pragma unroll
    for (int j = 0; j < 4; ++j) {
        int p = 250 + t + 64 * j;
        if (p < 500) conv1_pos(xbuf, y1s, w1, b1, p, p - 246);
    }
    __syncthreads();                     // xbuf dead; U becomes y2s

    // ---------------- conv2: 4->8ch, k=15, s=4 (+ y2s pad zeroing) --------
    if (t < 56) { int c = t / 7, k = t % 7;
                  y2s[c * 132 + (k < 3 ? k : 125 + k)] = 0.0f; }
#pragma unroll
    for (int jj = 0; jj < 2; ++jj) {
        int p = t + 64 * jj;
        if (p < 125) {
            float acc[8];
#pragma unroll
            for (int c = 0; c < 8; ++c) acc[c] = b2[c];
#pragma unroll
            for (int ci = 0; ci < 4; ++ci) {
                const float4* src = (const float4*)(y1s + 512 * ci);
                float xin[16];
#pragma unroll
                for (int j = 0; j < 4; ++j) {
                    float4 q = src[p + j];
                    xin[4 * j + 0] = q.x; xin[4 * j + 1] = q.y;
                    xin[4 * j + 2] = q.z; xin[4 * j + 3] = q.w;
                }
#pragma unroll
                for (int k = 0; k < 15; ++k) {
#pragma unroll
                    for (int c = 0; c < 8; ++c)
                        acc[c] += xin[k] * w2[(c * 4 + ci) * 15 + k];
                }
            }
#pragma unroll
            for (int c = 0; c < 8; ++c)
                y2s[c * 132 + 3 + p] = fmaxf(acc[c], 0.0f);
        }
    }
    __syncthreads();

    // ------- conv3: 8->16ch, k=7, s=4 + relu + mean; ctx ends in regs ------
    float ctx[16];
    if (t < 32) {
        float acc[16];
#pragma unroll
        for (int c = 0; c < 16; ++c) acc[c] = 0.0f;
#pragma unroll
        for (int ci = 0; ci < 8; ++ci) {
            const float4* src = (const float4*)(y2s + 132 * ci);
            float4 q0 = src[t];
            float4 q1 = src[t + 1];
            float xin[8] = {q0.x, q0.y, q0.z, q0.w, q1.x, q1.y, q1.z, q1.w};
#pragma unroll
            for (int k = 0; k < 7; ++k) {
#pragma unroll
                for (int c = 0; c < 16; ++c)
                    acc[c] += xin[k] * w3[(c * 8 + ci) * 7 + k];
            }
        }
#pragma unroll
        for (int c = 0; c < 16; ++c) {
            float v = fmaxf(acc[c] + b3[c], 0.0f);
            v += __shfl_xor(v, 16); v += __shfl_xor(v, 8);
            v += __shfl_xor(v, 4);  v += __shfl_xor(v, 2);
            v += __shfl_xor(v, 1);                  // all lanes 0..31 hold sum
            ctx[c] = v * (1.0f / 32.0f);
        }
    }
    // no barrier needed: ctx in registers, hs synced long ago, y2s dead

    // ---------------- GRU gates: gi on lanes 0..31, gh on lanes 32..63 -----
    float a0, a1, a2;
    if (t < 32) {
        const float* wr0 = w_ih + t * 19;
        const float* wr1 = w_ih + (32 + t) * 19;
        const float* wr2 = w_ih + (64 + t) * 19;
        a0 = b_ih[t]; a1 = b_ih[32 + t]; a2 = b_ih[64 + t];
#pragma unroll
        for (int j = 0; j < 16; ++j) {
            a0 += ctx[j] * wr0[j];
            a1 += ctx[j] * wr1[j];
            a2 += ctx[j] * wr2[j];
        }
        a0 += vel * wr0[16] + lpi * wr0[17] + tmi * wr0[18];
        a1 += vel * wr1[16] + lpi * wr1[17] + tmi * wr1[18];
        a2 += vel * wr2[16] + lpi * wr2[17] + tmi * wr2[18];
    } else {
        const int l = t - 32;
        const float4* wh0 = (const float4*)(w_hh + l * 32);
        const float4* wh1 = (const float4*)(w_hh + (32 + l) * 32);
        const float4* wh2 = (const float4*)(w_hh + (64 + l) * 32);
        a0 = b_hh[l]; a1 = b_hh[32 + l]; a2 = b_hh[64 + l];
        const float4* hv4 = (const float4*)hs;
#pragma unroll
        for (int j = 0; j < 8; ++j) {
            float4 h = hv4[j];              // broadcast LDS read
            float4 q0 = wh0[j], q1 = wh1[j], q2 = wh2[j];
            a0 += h.x * q0.x + h.y * q0.y + h.z * q0.z + h.w * q0.w;
            a1 += h.x * q1.x + h.y * q1.y + h.z * q1.z + h.w * q1.w;
            a2 += h.x * q2.x + h.y * q2.y + h.z * q2.z + h.w * q2.w;
        }
    }
    // exchange gi <-> gh across the half-waves
    const float o0 = __shfl_xor(a0, 32);
    const float o1 = __shfl_xor(a1, 32);
    const float o2 = __shfl_xor(a2, 32);

    // ---------------- combine + projection (lanes 0..31) ----------------
    if (t < 32) {
        const float r = 1.0f / (1.0f + expf(-(a0 + o0)));
        const float z = 1.0f / (1.0f + expf(-(a1 + o1)));
        const float n = tanhf(a2 + r * o2);
        const float h = hs[t];
        const float nh = (1.0f - z) * n + z * h;
        out[(size_t)2 * B + (size_t)b * 32 + t] = nh;   // new_hidden

        float p0 = nh * w_proj[t];
        float p1 = nh * w_proj[32 + t];
        p0 += __shfl_xor(p0, 16); p1 += __shfl_xor(p1, 16);
        p0 += __shfl_xor(p0, 8);  p1 += __shfl_xor(p1, 8);
        p0 += __shfl_xor(p0, 4);  p1 += __shfl_xor(p1, 4);
        p0 += __shfl_xor(p0, 2);  p1 += __shfl_xor(p1, 2);
        p0 += __shfl_xor(p0, 1);  p1 += __shfl_xor(p1, 1);
        if (t == 0) {
            out[b] = p0 + b_proj[0];                    // mu
            out[B + b] = expf(p1 + b_proj[1]);          // sigma
        }
    }
}

extern "C" void kernel_launch(void* const* d_in, const int* in_sizes, int n_in,
                              void* d_out, int out_size, void* d_ws, size_t ws_size,
                              hipStream_t stream)
{
    const float* past      = (const float*)d_in[0];
    const float* velocity  = (const float*)d_in[1];
    const float* log_pitch = (const float*)d_in[2];
    const float* time_in   = (const float*)d_in[3];
    const float* hidden    = (const float*)d_in[4];
    const float* w1  = (const float*)d_in[5];
    const float* b1  = (const float*)d_in[6];
    const float* w2  = (const float*)d_in[7];
    const float* b2  = (const float*)d_in[8];
    const float* w3  = (const float*)d_in[9];
    const float* b3  = (const float*)d_in[10];
    const float* wih = (const float*)d_in[11];
    const float* whh = (const float*)d_in[12];
    const float* bih = (const float*)d_in[13];
    const float* bhh = (const float*)d_in[14];
    const float* wpr = (const float*)d_in[15];
    const float* bpr = (const float*)d_in[16];

    const int B = in_sizes[0] / 2000;

    wavernn_fused<<<dim3(B), dim3(64), 0, stream>>>(
        past, velocity, log_pitch, time_in, hidden,
        w1, b1, w2, b2, w3, b3, wih, whh, bih, bhh, wpr, bpr,
        (float*)d_out, B);
}

// Round 4
// 584.323 us; speedup vs baseline: 1.0100x; 1.0100x over previous
//
#include <hip/hip_runtime.h>
#include <math.h>

// ---------------------------------------------------------------------------
// WaveRNN fused, wave-per-item, LDS-aliased: conv1(1->4,k31,s4,p15) -> relu ->
// conv2(4->8,k15,s4,p7) -> relu -> conv3(8->16,k7,s4,p3) -> relu -> mean ->
// GRU (H=32) -> proj.  64-thread (1-wave) blocks, one batch item each.
//
// LDS per block = 12544 B (y1s 2048f | U 1056f | hs 32f) -> 12 blocks/CU.
// U is time-multiplexed:
//   conv1 phase : xbuf (pad16 | 1016 staged floats | pad16) = 1048f
//   conv2+ phase: y2s  (8 ch x [pad3 | 125 | pad4])         = 1056f
// Round-3 lesson: NO live-across-phase register arrays for staging — the
// allocator spilled them to scratch (+64 MB HBM writes, 2x regression).
// Chunk-1 is staged with plain global->LDS stores after the chunk-0 barrier;
// 12 resident waves/CU hide that latency.
// Conv weight indexing is compile-time -> scalar s_load operands (K$-hot).
// ---------------------------------------------------------------------------

__device__ __forceinline__ void conv1_pos(const float* __restrict__ xbuf,
                                          float* __restrict__ y1s,
                                          const float* __restrict__ w1,
                                          const float* __restrict__ b1,
                                          int p, int q0)
{
    const float4* src = (const float4*)xbuf;
    float xin[32];
#pragma unroll
    for (int j = 0; j < 8; ++j) {
        float4 q = src[q0 + j];
        xin[4 * j + 0] = q.x; xin[4 * j + 1] = q.y;
        xin[4 * j + 2] = q.z; xin[4 * j + 3] = q.w;
    }
    float a0 = b1[0], a1 = b1[1], a2 = b1[2], a3 = b1[3];
#pragma unroll
    for (int k = 0; k < 31; ++k) {
        float xv = xin[k + 1];
        a0 += xv * w1[k];
        a1 += xv * w1[31 + k];
        a2 += xv * w1[62 + k];
        a3 += xv * w1[93 + k];
    }
    y1s[7 + p]        = fmaxf(a0, 0.0f);
    y1s[512 + 7 + p]  = fmaxf(a1, 0.0f);
    y1s[1024 + 7 + p] = fmaxf(a2, 0.0f);
    y1s[1536 + 7 + p] = fmaxf(a3, 0.0f);
}

__global__ void __launch_bounds__(64, 3)
wavernn_fused(const float* __restrict__ past,      // (B,2000)
              const float* __restrict__ velocity,  // (B,)
              const float* __restrict__ log_pitch, // (B,)
              const float* __restrict__ time_in,   // (B,)
              const float* __restrict__ hidden,    // (B,32)
              const float* __restrict__ w1, const float* __restrict__ b1,
              const float* __restrict__ w2, const float* __restrict__ b2,
              const float* __restrict__ w3, const float* __restrict__ b3,
              const float* __restrict__ w_ih, const float* __restrict__ w_hh,
              const float* __restrict__ b_ih, const float* __restrict__ b_hh,
              const float* __restrict__ w_proj, const float* __restrict__ b_proj,
              float* __restrict__ out, int B)
{
    __shared__ __align__(16) float smem[3136];
    float* const y1s  = smem;          // 2048 floats
    float* const U    = smem + 2048;   // 1056 floats (xbuf / y2s)
    float* const hs   = smem + 3104;   // 32 floats

    float* const xbuf = U;
    float* const y2s  = U;
    float4* const xb4 = (float4*)U;

    const int t = threadIdx.x;       // 0..63, single wave
    const int b = blockIdx.x;

    const float4* row4 = (const float4*)(past + (size_t)b * 2000);

    // wave-uniform scalars (s_load path)
    const float vel = velocity[b];
    const float lpi = log_pitch[b];
    const float tmi = time_in[b];

    // ---------------- pads + hidden stage + chunk0 stage ----------------
    if (t < 16) { xbuf[t] = 0.0f; xbuf[1032 + t] = 0.0f; }
    if (t < 48) { int c = t / 12, k = t % 12;
                  y1s[c * 512 + (k < 7 ? k : 500 + k)] = 0.0f; }
    if (t < 32) hs[t] = hidden[(size_t)b * 32 + t];

#pragma unroll
    for (int j = 0; j < 4; ++j) {
        int i = t + 64 * j;
        if (i < 254) xb4[4 + i] = row4[i];       // xbuf[16+4i] <- x[4i]
    }
    __syncthreads();

    // ---------------- conv1 chunk 0: positions 0..249 ----------------
#pragma unroll
    for (int j = 0; j < 4; ++j) {
        int p = t + 64 * j;
        if (p < 250) conv1_pos(xbuf, y1s, w1, b1, p, p);
    }
    __syncthreads();                     // WAR: all reads of xbuf done

    // ---------------- stage chunk 1: x[984..1999] ----------------
#pragma unroll
    for (int j = 0; j < 4; ++j) {
        int i = t + 64 * j;
        if (i < 254) xb4[4 + i] = row4[246 + i]; // xbuf[16+4i] <- x[984+4i]
    }
    __syncthreads();

    // ---------------- conv1 chunk 1: positions 250..499 ----------------
#pragma unroll
    for (int j = 0; j < 4; ++j) {
        int p = 250 + t + 64 * j;
        if (p < 500) conv1_pos(xbuf, y1s, w1, b1, p, p - 246);
    }
    __syncthreads();                     // xbuf dead; U becomes y2s

    // ---------------- conv2: 4->8ch, k=15, s=4 (+ y2s pad zeroing) --------
    if (t < 56) { int c = t / 7, k = t % 7;
                  y2s[c * 132 + (k < 3 ? k : 125 + k)] = 0.0f; }
#pragma unroll
    for (int jj = 0; jj < 2; ++jj) {
        int p = t + 64 * jj;
        if (p < 125) {
            float acc[8];
#pragma unroll
            for (int c = 0; c < 8; ++c) acc[c] = b2[c];
#pragma unroll
            for (int ci = 0; ci < 4; ++ci) {
                const float4* src = (const float4*)(y1s + 512 * ci);
                float xin[16];
#pragma unroll
                for (int j = 0; j < 4; ++j) {
                    float4 q = src[p + j];
                    xin[4 * j + 0] = q.x; xin[4 * j + 1] = q.y;
                    xin[4 * j + 2] = q.z; xin[4 * j + 3] = q.w;
                }
#pragma unroll
                for (int k = 0; k < 15; ++k) {
#pragma unroll
                    for (int c = 0; c < 8; ++c)
                        acc[c] += xin[k] * w2[(c * 4 + ci) * 15 + k];
                }
            }
#pragma unroll
            for (int c = 0; c < 8; ++c)
                y2s[c * 132 + 3 + p] = fmaxf(acc[c], 0.0f);
        }
    }
    __syncthreads();

    // ------- conv3: 8->16ch, k=7, s=4 + relu + mean; ctx ends in regs ------
    float ctx[16];
    if (t < 32) {
        float acc[16];
#pragma unroll
        for (int c = 0; c < 16; ++c) acc[c] = 0.0f;
#pragma unroll
        for (int ci = 0; ci < 8; ++ci) {
            const float4* src = (const float4*)(y2s + 132 * ci);
            float4 q0 = src[t];
            float4 q1 = src[t + 1];
            float xin[8] = {q0.x, q0.y, q0.z, q0.w, q1.x, q1.y, q1.z, q1.w};
#pragma unroll
            for (int k = 0; k < 7; ++k) {
#pragma unroll
                for (int c = 0; c < 16; ++c)
                    acc[c] += xin[k] * w3[(c * 8 + ci) * 7 + k];
            }
        }
#pragma unroll
        for (int c = 0; c < 16; ++c) {
            float v = fmaxf(acc[c] + b3[c], 0.0f);
            v += __shfl_xor(v, 16); v += __shfl_xor(v, 8);
            v += __shfl_xor(v, 4);  v += __shfl_xor(v, 2);
            v += __shfl_xor(v, 1);                  // all lanes 0..31 hold sum
            ctx[c] = v * (1.0f / 32.0f);
        }
    }
    // no barrier: ctx in registers, hs written long ago (same wave), y2s dead

    // ---------------- GRU gates: gi on lanes 0..31, gh on lanes 32..63 -----
    float a0, a1, a2;
    if (t < 32) {
        const float* wr0 = w_ih + t * 19;
        const float* wr1 = w_ih + (32 + t) * 19;
        const float* wr2 = w_ih + (64 + t) * 19;
        a0 = b_ih[t]; a1 = b_ih[32 + t]; a2 = b_ih[64 + t];
#pragma unroll
        for (int j = 0; j < 16; ++j) {
            a0 += ctx[j] * wr0[j];
            a1 += ctx[j] * wr1[j];
            a2 += ctx[j] * wr2[j];
        }
        a0 += vel * wr0[16] + lpi * wr0[17] + tmi * wr0[18];
        a1 += vel * wr1[16] + lpi * wr1[17] + tmi * wr1[18];
        a2 += vel * wr2[16] + lpi * wr2[17] + tmi * wr2[18];
    } else {
        const int l = t - 32;
        const float4* wh0 = (const float4*)(w_hh + l * 32);
        const float4* wh1 = (const float4*)(w_hh + (32 + l) * 32);
        const float4* wh2 = (const float4*)(w_hh + (64 + l) * 32);
        a0 = b_hh[l]; a1 = b_hh[32 + l]; a2 = b_hh[64 + l];
        const float4* hv4 = (const float4*)hs;
#pragma unroll
        for (int j = 0; j < 8; ++j) {
            float4 h = hv4[j];              // broadcast LDS read
            float4 q0 = wh0[j], q1 = wh1[j], q2 = wh2[j];
            a0 += h.x * q0.x + h.y * q0.y + h.z * q0.z + h.w * q0.w;
            a1 += h.x * q1.x + h.y * q1.y + h.z * q1.z + h.w * q1.w;
            a2 += h.x * q2.x + h.y * q2.y + h.z * q2.z + h.w * q2.w;
        }
    }
    // exchange gi <-> gh across the half-waves
    const float o0 = __shfl_xor(a0, 32);
    const float o1 = __shfl_xor(a1, 32);
    const float o2 = __shfl_xor(a2, 32);

    // ---------------- combine + projection (lanes 0..31) ----------------
    if (t < 32) {
        const float r = 1.0f / (1.0f + expf(-(a0 + o0)));
        const float z = 1.0f / (1.0f + expf(-(a1 + o1)));
        const float n = tanhf(a2 + r * o2);
        const float h = hs[t];
        const float nh = (1.0f - z) * n + z * h;
        out[(size_t)2 * B + (size_t)b * 32 + t] = nh;   // new_hidden

        float p0 = nh * w_proj[t];
        float p1 = nh * w_proj[32 + t];
        p0 += __shfl_xor(p0, 16); p1 += __shfl_xor(p1, 16);
        p0 += __shfl_xor(p0, 8);  p1 += __shfl_xor(p1, 8);
        p0 += __shfl_xor(p0, 4);  p1 += __shfl_xor(p1, 4);
        p0 += __shfl_xor(p0, 2);  p1 += __shfl_xor(p1, 2);
        p0 += __shfl_xor(p0, 1);  p1 += __shfl_xor(p1, 1);
        if (t == 0) {
            out[b] = p0 + b_proj[0];                    // mu
            out[B + b] = expf(p1 + b_proj[1]);          // sigma
        }
    }
}

extern "C" void kernel_launch(void* const* d_in, const int* in_sizes, int n_in,
                              void* d_out, int out_size, void* d_ws, size_t ws_size,
                              hipStream_t stream)
{
    const float* past      = (const float*)d_in[0];
    const float* velocity  = (const float*)d_in[1];
    const float* log_pitch = (const float*)d_in[2];
    const float* time_in   = (const float*)d_in[3];
    const float* hidden    = (const float*)d_in[4];
    const float* w1  = (const float*)d_in[5];
    const float* b1  = (const float*)d_in[6];
    const float* w2  = (const float*)d_in[7];
    const float* b2  = (const float*)d_in[8];
    const float* w3  = (const float*)d_in[9];
    const float* b3  = (const float*)d_in[10];
    const float* wih = (const float*)d_in[11];
    const float* whh = (const float*)d_in[12];
    const float* bih = (const float*)d_in[13];
    const float* bhh = (const float*)d_in[14];
    const float* wpr = (const float*)d_in[15];
    const float* bpr = (const float*)d_in[16];

    const int B = in_sizes[0] / 2000;

    wavernn_fused<<<dim3(B), dim3(64), 0, stream>>>(
        past, velocity, log_pitch, time_in, hidden,
        w1, b1, w2, b2, w3, b3, wih, whh, bih, bhh, wpr, bpr,
        (float*)d_out, B);
}

// Round 5
// 344.421 us; speedup vs baseline: 1.7134x; 1.6965x over previous
//
#include <hip/hip_runtime.h>
#include <math.h>

// ---------------------------------------------------------------------------
// WaveRNN fused, wave-per-item. EXACT round-2 instruction stream (225 us,
// known good) + ONE change: LDS time-aliasing of xbuf/y2s/gis+ghs into a
// single X[1056] region -> 12624 B/block (reports 12800) -> 12 blocks/CU
// (vs round-2's 17.9 KB / 9 blocks).  y1s/rnn/hs stay separate arrays to
// preserve round-2's alias structure.  Round-3/4 post-mortem: the register-
// ctx / half-wave-shfl GRU restructure (NOT the spill) carried a hidden ~2x
// regression; this round isolates the occupancy lever alone.
//
// X timeline:  conv1 phase: xbuf (pad16 | 1016 | pad16)
//              conv2/conv3 : y2s (8 ch x [pad3 | 125 | pad4])
//              GRU phase   : gis[96] | ghs[96]
// Each handoff is separated by an existing __syncthreads().
// ---------------------------------------------------------------------------

__device__ __forceinline__ void conv1_pos(const float* __restrict__ xbuf,
                                          float* __restrict__ y1s,
                                          const float* __restrict__ w1,
                                          const float* __restrict__ b1,
                                          int p, int q0)
{
    const float4* src = (const float4*)xbuf;
    float xin[32];
#pragma unroll
    for (int j = 0; j < 8; ++j) {
        float4 q = src[q0 + j];
        xin[4 * j + 0] = q.x; xin[4 * j + 1] = q.y;
        xin[4 * j + 2] = q.z; xin[4 * j + 3] = q.w;
    }
    float a0 = b1[0], a1 = b1[1], a2 = b1[2], a3 = b1[3];
#pragma unroll
    for (int k = 0; k < 31; ++k) {
        float xv = xin[k + 1];
        a0 += xv * w1[k];
        a1 += xv * w1[31 + k];
        a2 += xv * w1[62 + k];
        a3 += xv * w1[93 + k];
    }
    y1s[7 + p]        = fmaxf(a0, 0.0f);
    y1s[512 + 7 + p]  = fmaxf(a1, 0.0f);
    y1s[1024 + 7 + p] = fmaxf(a2, 0.0f);
    y1s[1536 + 7 + p] = fmaxf(a3, 0.0f);
}

__global__ void __launch_bounds__(64, 3)
wavernn_fused(const float* __restrict__ past,      // (B,2000)
              const float* __restrict__ velocity,  // (B,)
              const float* __restrict__ log_pitch, // (B,)
              const float* __restrict__ time_in,   // (B,)
              const float* __restrict__ hidden,    // (B,32)
              const float* __restrict__ w1, const float* __restrict__ b1,
              const float* __restrict__ w2, const float* __restrict__ b2,
              const float* __restrict__ w3, const float* __restrict__ b3,
              const float* __restrict__ w_ih, const float* __restrict__ w_hh,
              const float* __restrict__ b_ih, const float* __restrict__ b_hh,
              const float* __restrict__ w_proj, const float* __restrict__ b_proj,
              float* __restrict__ out, int B)
{
    __shared__ __align__(16) float X[1056];    // xbuf -> y2s -> gis|ghs
    __shared__ __align__(16) float y1s[2048];
    __shared__ float rnn[20];   // [0..15]=ctx, 16=vel, 17=log_pitch, 18=time
    __shared__ float hs[32];

    float* const xbuf = X;
    float* const y2s  = X;
    float* const gis  = X;          // GRU phase only (y2s dead)
    float* const ghs  = X + 96;
    float4* const xb4 = (float4*)X;

    const int t = threadIdx.x;       // 0..63, single wave
    const int b = blockIdx.x;

    const float4* row4 = (const float4*)(past + (size_t)b * 2000);

    // ---------------- pads + small stages + chunk0 stage ----------------
    if (t < 16) { xbuf[t] = 0.0f; xbuf[1032 + t] = 0.0f; }
    if (t < 48) { int c = t / 12, k = t % 12;
                  y1s[c * 512 + (k < 7 ? k : 500 + k)] = 0.0f; }
    if (t < 32) hs[t] = hidden[(size_t)b * 32 + t];
    if (t == 0) rnn[16] = velocity[b];
    if (t == 1) rnn[17] = log_pitch[b];
    if (t == 2) rnn[18] = time_in[b];

#pragma unroll
    for (int j = 0; j < 4; ++j) {
        int i = t + 64 * j;
        if (i < 254) xb4[4 + i] = row4[i];       // xbuf[16+4i] <- x[4i]
    }
    __syncthreads();

    // ---------------- conv1 chunk 0: positions 0..249 ----------------
#pragma unroll
    for (int j = 0; j < 4; ++j) {
        int p = t + 64 * j;
        if (p < 250) conv1_pos(xbuf, y1s, w1, b1, p, p);
    }
    __syncthreads();                     // WAR: all reads of xbuf done

    // ---------------- stage chunk 1: x[984..1999] ----------------
#pragma unroll
    for (int j = 0; j < 4; ++j) {
        int i = t + 64 * j;
        if (i < 254) xb4[4 + i] = row4[246 + i]; // xbuf[16+4i] <- x[984+4i]
    }
    __syncthreads();

    // ---------------- conv1 chunk 1: positions 250..499 ----------------
#pragma unroll
    for (int j = 0; j < 4; ++j) {
        int p = 250 + t + 64 * j;
        if (p < 500) conv1_pos(xbuf, y1s, w1, b1, p, p - 246);
    }
    __syncthreads();                     // xbuf dead; X becomes y2s

    // ---------------- conv2: 4->8ch, k=15, s=4 (+ y2s pad zeroing) --------
    if (t < 56) { int c = t / 7, k = t % 7;
                  y2s[c * 132 + (k < 3 ? k : 125 + k)] = 0.0f; }
#pragma unroll
    for (int jj = 0; jj < 2; ++jj) {
        int p = t + 64 * jj;
        if (p < 125) {
            float acc[8];
#pragma unroll
            for (int c = 0; c < 8; ++c) acc[c] = b2[c];
#pragma unroll
            for (int ci = 0; ci < 4; ++ci) {
                const float4* src = (const float4*)(y1s + 512 * ci);
                float xin[16];
#pragma unroll
                for (int j = 0; j < 4; ++j) {
                    float4 q = src[p + j];
                    xin[4 * j + 0] = q.x; xin[4 * j + 1] = q.y;
                    xin[4 * j + 2] = q.z; xin[4 * j + 3] = q.w;
                }
#pragma unroll
                for (int k = 0; k < 15; ++k) {
#pragma unroll
                    for (int c = 0; c < 8; ++c)
                        acc[c] += xin[k] * w2[(c * 4 + ci) * 15 + k];
                }
            }
#pragma unroll
            for (int c = 0; c < 8; ++c)
                y2s[c * 132 + 3 + p] = fmaxf(acc[c], 0.0f);
        }
    }
    __syncthreads();

    // ------- conv3: 8->16ch, k=7, s=4 + relu + mean (lanes 0..31) ----------
    if (t < 32) {
        float acc[16];
#pragma unroll
        for (int c = 0; c < 16; ++c) acc[c] = 0.0f;
#pragma unroll
        for (int ci = 0; ci < 8; ++ci) {
            const float4* src = (const float4*)(y2s + 132 * ci);
            float4 q0 = src[t];
            float4 q1 = src[t + 1];
            float xin[8] = {q0.x, q0.y, q0.z, q0.w, q1.x, q1.y, q1.z, q1.w};
#pragma unroll
            for (int k = 0; k < 7; ++k) {
#pragma unroll
                for (int c = 0; c < 16; ++c)
                    acc[c] += xin[k] * w3[(c * 8 + ci) * 7 + k];
            }
        }
#pragma unroll
        for (int c = 0; c < 16; ++c) {
            float v = fmaxf(acc[c] + b3[c], 0.0f);
            v += __shfl_xor(v, 16); v += __shfl_xor(v, 8);
            v += __shfl_xor(v, 4);  v += __shfl_xor(v, 2);
            v += __shfl_xor(v, 1);
            if (t == 0) rnn[c] = v * (1.0f / 32.0f);
        }
    }
    __syncthreads();                    // y2s dead; X becomes gis|ghs

    // ---------------- GRU gates (round-2 structure, LDS-based) -------------
    {
        float rv[19];
#pragma unroll
        for (int j = 0; j < 19; ++j) rv[j] = rnn[j];

        float a = b_ih[t];
        const float* wr = w_ih + t * 19;
#pragma unroll
        for (int j = 0; j < 19; ++j) a += rv[j] * wr[j];
        gis[t] = a;
        if (t < 32) {
            float a2 = b_ih[64 + t];
            const float* wr2 = w_ih + (64 + t) * 19;
#pragma unroll
            for (int j = 0; j < 19; ++j) a2 += rv[j] * wr2[j];
            gis[64 + t] = a2;
        }

        float hv[32];
#pragma unroll
        for (int j = 0; j < 32; ++j) hv[j] = hs[j];

        float g = b_hh[t];
        const float4* wh = (const float4*)(w_hh + t * 32);
#pragma unroll
        for (int j = 0; j < 8; ++j) {
            float4 q = wh[j];
            g += hv[4 * j] * q.x + hv[4 * j + 1] * q.y +
                 hv[4 * j + 2] * q.z + hv[4 * j + 3] * q.w;
        }
        ghs[t] = g;
        if (t < 32) {
            float g2 = b_hh[64 + t];
            const float4* wh2 = (const float4*)(w_hh + (64 + t) * 32);
#pragma unroll
            for (int j = 0; j < 8; ++j) {
                float4 q = wh2[j];
                g2 += hv[4 * j] * q.x + hv[4 * j + 1] * q.y +
                      hv[4 * j + 2] * q.z + hv[4 * j + 3] * q.w;
            }
            ghs[64 + t] = g2;
        }
    }
    __syncthreads();

    // ---------------- combine + projection (lanes 0..31) ----------------
    if (t < 32) {
        const int j = t;
        float r = 1.0f / (1.0f + expf(-(gis[j] + ghs[j])));
        float z = 1.0f / (1.0f + expf(-(gis[32 + j] + ghs[32 + j])));
        float n = tanhf(gis[64 + j] + r * ghs[64 + j]);
        float nh = (1.0f - z) * n + z * hs[j];
        out[(size_t)2 * B + (size_t)b * 32 + j] = nh;   // new_hidden

        float p0 = nh * w_proj[j];
        float p1 = nh * w_proj[32 + j];
        p0 += __shfl_xor(p0, 16); p1 += __shfl_xor(p1, 16);
        p0 += __shfl_xor(p0, 8);  p1 += __shfl_xor(p1, 8);
        p0 += __shfl_xor(p0, 4);  p1 += __shfl_xor(p1, 4);
        p0 += __shfl_xor(p0, 2);  p1 += __shfl_xor(p1, 2);
        p0 += __shfl_xor(p0, 1);  p1 += __shfl_xor(p1, 1);
        if (j == 0) {
            out[b] = p0 + b_proj[0];                    // mu
            out[B + b] = expf(p1 + b_proj[1]);          // sigma
        }
    }
}

extern "C" void kernel_launch(void* const* d_in, const int* in_sizes, int n_in,
                              void* d_out, int out_size, void* d_ws, size_t ws_size,
                              hipStream_t stream)
{
    const float* past      = (const float*)d_in[0];
    const float* velocity  = (const float*)d_in[1];
    const float* log_pitch = (const float*)d_in[2];
    const float* time_in   = (const float*)d_in[3];
    const float* hidden    = (const float*)d_in[4];
    const float* w1  = (const float*)d_in[5];
    const float* b1  = (const float*)d_in[6];
    const float* w2  = (const float*)d_in[7];
    const float* b2  = (const float*)d_in[8];
    const float* w3  = (const float*)d_in[9];
    const float* b3  = (const float*)d_in[10];
    const float* wih = (const float*)d_in[11];
    const float* whh = (const float*)d_in[12];
    const float* bih = (const float*)d_in[13];
    const float* bhh = (const float*)d_in[14];
    const float* wpr = (const float*)d_in[15];
    const float* bpr = (const float*)d_in[16];

    const int B = in_sizes[0] / 2000;

    wavernn_fused<<<dim3(B), dim3(64), 0, stream>>>(
        past, velocity, log_pitch, time_in, hidden,
        w1, b1, w2, b2, w3, b3, wih, whh, bih, bhh, wpr, bpr,
        (float*)d_out, B);
}

// Round 6
// 318.536 us; speedup vs baseline: 1.8527x; 1.0813x over previous
//
#include <hip/hip_runtime.h>
#include <hip/hip_fp16.h>
#include <math.h>

// ---------------------------------------------------------------------------
// WaveRNN fused, wave-per-item. Round-5 structure (190 us) + ONE change:
// y1 (conv1 output) stored in LDS as fp16 instead of fp32 -> 8528 B/block
// (reports 8704) -> 18 blocks/CU (vs 12).  Values are O(1); fp16 error
// ~5e-4 vs threshold 7.6e-2.
//
// LDS:  X[1056]f   : xbuf (pad16|1016|pad16) -> y2s (8x[pad3|125|pad4])
//                    -> gis[96]|ghs[96]        (handoffs at __syncthreads)
//       y1h[2048]h : 4 ch x [pad7 | 500 | pad5] halfs (1024 B/plane)
//       rnn[20]f, hs[32]f
// conv2 reads y1 window [4p-7..4p+7] = stored halfs [4p..4p+14]: 8 lane-
// contiguous __half2 (b32) loads from half2 idx 2p.. (4B aligned).
// Known-poison avoided: no live-across-phase register staging arrays (R3),
// no half-wave-shfl GRU restructure (R3/R4).
// ---------------------------------------------------------------------------

__device__ __forceinline__ void conv1_pos(const float* __restrict__ xbuf,
                                          __half* __restrict__ y1h,
                                          const float* __restrict__ w1,
                                          const float* __restrict__ b1,
                                          int p, int q0)
{
    const float4* src = (const float4*)xbuf;
    float xin[32];
#pragma unroll
    for (int j = 0; j < 8; ++j) {
        float4 q = src[q0 + j];
        xin[4 * j + 0] = q.x; xin[4 * j + 1] = q.y;
        xin[4 * j + 2] = q.z; xin[4 * j + 3] = q.w;
    }
    float a0 = b1[0], a1 = b1[1], a2 = b1[2], a3 = b1[3];
#pragma unroll
    for (int k = 0; k < 31; ++k) {
        float xv = xin[k + 1];
        a0 += xv * w1[k];
        a1 += xv * w1[31 + k];
        a2 += xv * w1[62 + k];
        a3 += xv * w1[93 + k];
    }
    y1h[7 + p]        = __float2half_rn(fmaxf(a0, 0.0f));
    y1h[512 + 7 + p]  = __float2half_rn(fmaxf(a1, 0.0f));
    y1h[1024 + 7 + p] = __float2half_rn(fmaxf(a2, 0.0f));
    y1h[1536 + 7 + p] = __float2half_rn(fmaxf(a3, 0.0f));
}

__global__ void __launch_bounds__(64, 3)
wavernn_fused(const float* __restrict__ past,      // (B,2000)
              const float* __restrict__ velocity,  // (B,)
              const float* __restrict__ log_pitch, // (B,)
              const float* __restrict__ time_in,   // (B,)
              const float* __restrict__ hidden,    // (B,32)
              const float* __restrict__ w1, const float* __restrict__ b1,
              const float* __restrict__ w2, const float* __restrict__ b2,
              const float* __restrict__ w3, const float* __restrict__ b3,
              const float* __restrict__ w_ih, const float* __restrict__ w_hh,
              const float* __restrict__ b_ih, const float* __restrict__ b_hh,
              const float* __restrict__ w_proj, const float* __restrict__ b_proj,
              float* __restrict__ out, int B)
{
    __shared__ __align__(16) float X[1056];      // xbuf -> y2s -> gis|ghs
    __shared__ __align__(16) __half y1h[2048];   // 4 ch x 512 halfs
    __shared__ float rnn[20];   // [0..15]=ctx, 16=vel, 17=log_pitch, 18=time
    __shared__ float hs[32];

    float* const xbuf = X;
    float* const y2s  = X;
    float* const gis  = X;          // GRU phase only (y2s dead)
    float* const ghs  = X + 96;
    float4* const xb4 = (float4*)X;

    const int t = threadIdx.x;       // 0..63, single wave
    const int b = blockIdx.x;

    const float4* row4 = (const float4*)(past + (size_t)b * 2000);

    // ---------------- pads + small stages + chunk0 stage ----------------
    if (t < 16) { xbuf[t] = 0.0f; xbuf[1032 + t] = 0.0f; }
    if (t < 48) { int c = t / 12, k = t % 12;
                  y1h[c * 512 + (k < 7 ? k : 500 + k)] = __float2half_rn(0.0f); }
    if (t < 32) hs[t] = hidden[(size_t)b * 32 + t];
    if (t == 0) rnn[16] = velocity[b];
    if (t == 1) rnn[17] = log_pitch[b];
    if (t == 2) rnn[18] = time_in[b];

#pragma unroll
    for (int j = 0; j < 4; ++j) {
        int i = t + 64 * j;
        if (i < 254) xb4[4 + i] = row4[i];       // xbuf[16+4i] <- x[4i]
    }
    __syncthreads();

    // ---------------- conv1 chunk 0: positions 0..249 ----------------
#pragma unroll
    for (int j = 0; j < 4; ++j) {
        int p = t + 64 * j;
        if (p < 250) conv1_pos(xbuf, y1h, w1, b1, p, p);
    }
    __syncthreads();                     // WAR: all reads of xbuf done

    // ---------------- stage chunk 1: x[984..1999] ----------------
#pragma unroll
    for (int j = 0; j < 4; ++j) {
        int i = t + 64 * j;
        if (i < 254) xb4[4 + i] = row4[246 + i]; // xbuf[16+4i] <- x[984+4i]
    }
    __syncthreads();

    // ---------------- conv1 chunk 1: positions 250..499 ----------------
#pragma unroll
    for (int j = 0; j < 4; ++j) {
        int p = 250 + t + 64 * j;
        if (p < 500) conv1_pos(xbuf, y1h, w1, b1, p, p - 246);
    }
    __syncthreads();                     // xbuf dead; X becomes y2s

    // ---------------- conv2: 4->8ch, k=15, s=4 (+ y2s pad zeroing) --------
    if (t < 56) { int c = t / 7, k = t % 7;
                  y2s[c * 132 + (k < 3 ? k : 125 + k)] = 0.0f; }
#pragma unroll
    for (int jj = 0; jj < 2; ++jj) {
        int p = t + 64 * jj;
        if (p < 125) {
            float acc[8];
#pragma unroll
            for (int c = 0; c < 8; ++c) acc[c] = b2[c];
#pragma unroll
            for (int ci = 0; ci < 4; ++ci) {
                // stored halfs [4p .. 4p+14] == data idx [4p-7 .. 4p+7]
                const __half2* src = (const __half2*)(y1h + 512 * ci);
                float xin[16];
#pragma unroll
                for (int j = 0; j < 8; ++j) {
                    float2 f = __half22float2(src[2 * p + j]);
                    xin[2 * j]     = f.x;
                    xin[2 * j + 1] = f.y;
                }
#pragma unroll
                for (int k = 0; k < 15; ++k) {
#pragma unroll
                    for (int c = 0; c < 8; ++c)
                        acc[c] += xin[k] * w2[(c * 4 + ci) * 15 + k];
                }
            }
#pragma unroll
            for (int c = 0; c < 8; ++c)
                y2s[c * 132 + 3 + p] = fmaxf(acc[c], 0.0f);
        }
    }
    __syncthreads();

    // ------- conv3: 8->16ch, k=7, s=4 + relu + mean (lanes 0..31) ----------
    if (t < 32) {
        float acc[16];
#pragma unroll
        for (int c = 0; c < 16; ++c) acc[c] = 0.0f;
#pragma unroll
        for (int ci = 0; ci < 8; ++ci) {
            const float4* src = (const float4*)(y2s + 132 * ci);
            float4 q0 = src[t];
            float4 q1 = src[t + 1];
            float xin[8] = {q0.x, q0.y, q0.z, q0.w, q1.x, q1.y, q1.z, q1.w};
#pragma unroll
            for (int k = 0; k < 7; ++k) {
#pragma unroll
                for (int c = 0; c < 16; ++c)
                    acc[c] += xin[k] * w3[(c * 8 + ci) * 7 + k];
            }
        }
#pragma unroll
        for (int c = 0; c < 16; ++c) {
            float v = fmaxf(acc[c] + b3[c], 0.0f);
            v += __shfl_xor(v, 16); v += __shfl_xor(v, 8);
            v += __shfl_xor(v, 4);  v += __shfl_xor(v, 2);
            v += __shfl_xor(v, 1);
            if (t == 0) rnn[c] = v * (1.0f / 32.0f);
        }
    }
    __syncthreads();                    // y2s dead; X becomes gis|ghs

    // ---------------- GRU gates (round-2 structure, LDS-based) -------------
    {
        float rv[19];
#pragma unroll
        for (int j = 0; j < 19; ++j) rv[j] = rnn[j];

        float a = b_ih[t];
        const float* wr = w_ih + t * 19;
#pragma unroll
        for (int j = 0; j < 19; ++j) a += rv[j] * wr[j];
        gis[t] = a;
        if (t < 32) {
            float a2 = b_ih[64 + t];
            const float* wr2 = w_ih + (64 + t) * 19;
#pragma unroll
            for (int j = 0; j < 19; ++j) a2 += rv[j] * wr2[j];
            gis[64 + t] = a2;
        }

        float hv[32];
#pragma unroll
        for (int j = 0; j < 32; ++j) hv[j] = hs[j];

        float g = b_hh[t];
        const float4* wh = (const float4*)(w_hh + t * 32);
#pragma unroll
        for (int j = 0; j < 8; ++j) {
            float4 q = wh[j];
            g += hv[4 * j] * q.x + hv[4 * j + 1] * q.y +
                 hv[4 * j + 2] * q.z + hv[4 * j + 3] * q.w;
        }
        ghs[t] = g;
        if (t < 32) {
            float g2 = b_hh[64 + t];
            const float4* wh2 = (const float4*)(w_hh + (64 + t) * 32);
#pragma unroll
            for (int j = 0; j < 8; ++j) {
                float4 q = wh2[j];
                g2 += hv[4 * j] * q.x + hv[4 * j + 1] * q.y +
                      hv[4 * j + 2] * q.z + hv[4 * j + 3] * q.w;
            }
            ghs[64 + t] = g2;
        }
    }
    __syncthreads();

    // ---------------- combine + projection (lanes 0..31) ----------------
    if (t < 32) {
        const int j = t;
        float r = 1.0f / (1.0f + expf(-(gis[j] + ghs[j])));
        float z = 1.0f / (1.0f + expf(-(gis[32 + j] + ghs[32 + j])));
        float n = tanhf(gis[64 + j] + r * ghs[64 + j]);
        float nh = (1.0f - z) * n + z * hs[j];
        out[(size_t)2 * B + (size_t)b * 32 + j] = nh;   // new_hidden

        float p0 = nh * w_proj[j];
        float p1 = nh * w_proj[32 + j];
        p0 += __shfl_xor(p0, 16); p1 += __shfl_xor(p1, 16);
        p0 += __shfl_xor(p0, 8);  p1 += __shfl_xor(p1, 8);
        p0 += __shfl_xor(p0, 4);  p1 += __shfl_xor(p1, 4);
        p0 += __shfl_xor(p0, 2);  p1 += __shfl_xor(p1, 2);
        p0 += __shfl_xor(p0, 1);  p1 += __shfl_xor(p1, 1);
        if (j == 0) {
            out[b] = p0 + b_proj[0];                    // mu
            out[B + b] = expf(p1 + b_proj[1]);          // sigma
        }
    }
}

extern "C" void kernel_launch(void* const* d_in, const int* in_sizes, int n_in,
                              void* d_out, int out_size, void* d_ws, size_t ws_size,
                              hipStream_t stream)
{
    const float* past      = (const float*)d_in[0];
    const float* velocity  = (const float*)d_in[1];
    const float* log_pitch = (const float*)d_in[2];
    const float* time_in   = (const float*)d_in[3];
    const float* hidden    = (const float*)d_in[4];
    const float* w1  = (const float*)d_in[5];
    const float* b1  = (const float*)d_in[6];
    const float* w2  = (const float*)d_in[7];
    const float* b2  = (const float*)d_in[8];
    const float* w3  = (const float*)d_in[9];
    const float* b3  = (const float*)d_in[10];
    const float* wih = (const float*)d_in[11];
    const float* whh = (const float*)d_in[12];
    const float* bih = (const float*)d_in[13];
    const float* bhh = (const float*)d_in[14];
    const float* wpr = (const float*)d_in[15];
    const float* bpr = (const float*)d_in[16];

    const int B = in_sizes[0] / 2000;

    wavernn_fused<<<dim3(B), dim3(64), 0, stream>>>(
        past, velocity, log_pitch, time_in, hidden,
        w1, b1, w2, b2, w3, b3, wih, whh, bih, bhh, wpr, bpr,
        (float*)d_out, B);
}

// Round 7
// 271.854 us; speedup vs baseline: 2.1708x; 1.1717x over previous
//
#include <hip/hip_runtime.h>
#include <hip/hip_fp16.h>
#include <math.h>

// ---------------------------------------------------------------------------
// WaveRNN fused, wave-per-item, fp16-LDS + v_dot2_f32_f16 convs.
// Structure identical to round 6 (167 us) except:
//  (1) all conv activations stored in LDS as _Float16 (xbuf/y1/y2),
//  (2) conv inner loops use __builtin_amdgcn_fdot2 (2 fp16 MAC, fp32 acc),
//      weights repacked once per launch into d_ws as zero-padded half2 pairs
//      by a prep kernel; consumed at compile-time indices -> s_load path.
// LDS/block: X 2112 B (xbuf 1048h -> y2s 1056h -> gis|ghs 192f) +
//            y1h 4096 B + rnn 80 B + hs 128 B  = 6416 B -> 24 blocks/CU.
// All conv reads are 8B-aligned ds_read_b64 (2-way bank aliasing = free).
// GRU phase (fp32, LDS-based) byte-identical to round 6.
// Known poisons avoided: no live-across-phase register staging (R3),
// no half-wave-shfl GRU (R3/R4).
// ---------------------------------------------------------------------------

typedef _Float16 h2 __attribute__((ext_vector_type(2)));
typedef _Float16 h4 __attribute__((ext_vector_type(4)));

__device__ __forceinline__ float fdot2(h2 a, h2 b, float c)
{
#if defined(__has_builtin)
#if __has_builtin(__builtin_amdgcn_fdot2)
    return __builtin_amdgcn_fdot2(a, b, c, false);
#else
    return c + (float)a.x * (float)b.x + (float)a.y * (float)b.y;
#endif
#else
    return c + (float)a.x * (float)b.x + (float)a.y * (float)b.y;
#endif
}

// Pack conv weights into zero-padded half2 pairs in d_ws:
//   [0,64)    w1p: c(4) x 16 pairs, pair j covers taps (2j-1, 2j)   [tap -1 = 0]
//   [64,320)  w2p: (c*4+ci)(32) x 8 pairs, taps (2j, 2j+1), tap 15 = 0
//   [320,832) w3p: (c*8+ci)(128) x 4 pairs, taps (2j, 2j+1), tap 7 = 0
__global__ void pack_weights(const float* __restrict__ w1,
                             const float* __restrict__ w2,
                             const float* __restrict__ w3,
                             h2* __restrict__ ws)
{
    for (int idx = threadIdx.x; idx < 832; idx += 256) {
        float f0, f1;
        if (idx < 64) {
            int c = idx >> 4, jp = idx & 15;
            int j0 = 2 * jp, j1 = j0 + 1;
            f0 = (j0 == 0) ? 0.0f : w1[c * 31 + j0 - 1];
            f1 = w1[c * 31 + j1 - 1];
        } else if (idx < 320) {
            int r = idx - 64, cc = r >> 3, jp = r & 7;
            int j0 = 2 * jp, j1 = j0 + 1;
            f0 = w2[cc * 15 + j0];
            f1 = (j1 < 15) ? w2[cc * 15 + j1] : 0.0f;
        } else {
            int r = idx - 320, cc = r >> 2, jp = r & 3;
            int j0 = 2 * jp, j1 = j0 + 1;
            f0 = (j0 < 7) ? w3[cc * 7 + j0] : 0.0f;
            f1 = (j1 < 7) ? w3[cc * 7 + j1] : 0.0f;
        }
        ws[idx] = (h2){(_Float16)f0, (_Float16)f1};
    }
}

// conv1 at position p: window = stored halfs [h0 .. h0+31]; pair j covers
// (h0+2j, h0+2j+1); w1p pair 0 = (0, w[0]) absorbs the odd window start.
__device__ __forceinline__ void conv1_pos(const _Float16* __restrict__ xh,
                                          _Float16* __restrict__ y1h,
                                          const h2* __restrict__ w1p,
                                          const float* __restrict__ b1,
                                          int p, int h0)
{
    const h4* src = (const h4*)(xh + h0);        // byte 2*h0, 8B aligned
    h2 xp[16];
#pragma unroll
    for (int j = 0; j < 8; ++j) {
        h4 v = src[j];
        xp[2 * j]     = (h2){v.x, v.y};
        xp[2 * j + 1] = (h2){v.z, v.w};
    }
    float a0 = b1[0], a1 = b1[1], a2 = b1[2], a3 = b1[3];
#pragma unroll
    for (int j = 0; j < 16; ++j) {
        a0 = fdot2(xp[j], w1p[j],      a0);
        a1 = fdot2(xp[j], w1p[16 + j], a1);
        a2 = fdot2(xp[j], w1p[32 + j], a2);
        a3 = fdot2(xp[j], w1p[48 + j], a3);
    }
    y1h[7 + p]        = (_Float16)fmaxf(a0, 0.0f);
    y1h[512 + 7 + p]  = (_Float16)fmaxf(a1, 0.0f);
    y1h[1024 + 7 + p] = (_Float16)fmaxf(a2, 0.0f);
    y1h[1536 + 7 + p] = (_Float16)fmaxf(a3, 0.0f);
}

__global__ void __launch_bounds__(64, 3)
wavernn_fused(const float* __restrict__ past,      // (B,2000)
              const float* __restrict__ velocity,  // (B,)
              const float* __restrict__ log_pitch, // (B,)
              const float* __restrict__ time_in,   // (B,)
              const float* __restrict__ hidden,    // (B,32)
              const float* __restrict__ b1,
              const float* __restrict__ b2,
              const float* __restrict__ b3,
              const float* __restrict__ w_ih, const float* __restrict__ w_hh,
              const float* __restrict__ b_ih, const float* __restrict__ b_hh,
              const float* __restrict__ w_proj, const float* __restrict__ b_proj,
              const h2* __restrict__ wsp,          // packed conv weights
              float* __restrict__ out, int B)
{
    __shared__ __align__(16) _Float16 X[1056];    // xbuf -> y2s -> gis|ghs
    __shared__ __align__(16) _Float16 y1h[2048];  // 4 ch x [pad7|500|pad5]
    __shared__ float rnn[20];   // [0..15]=ctx, 16=vel, 17=log_pitch, 18=time
    __shared__ float hs[32];

    _Float16* const xbuf = X;                     // conv1 phase
    _Float16* const y2h  = X;                     // conv2/3 phase
    float* const gis     = (float*)X;             // GRU phase
    float* const ghs     = (float*)X + 96;

    const h2* const w1p = wsp;
    const h2* const w2p = wsp + 64;
    const h2* const w3p = wsp + 320;

    const int t = threadIdx.x;       // 0..63, single wave
    const int b = blockIdx.x;

    const float4* row4 = (const float4*)(past + (size_t)b * 2000);

    // ---------------- pads + small stages + chunk0 stage ----------------
    if (t < 16) { xbuf[t] = (_Float16)0.0f; xbuf[1032 + t] = (_Float16)0.0f; }
    if (t < 48) { int c = t / 12, k = t % 12;
                  y1h[c * 512 + (k < 7 ? k : 500 + k)] = (_Float16)0.0f; }
    if (t < 32) hs[t] = hidden[(size_t)b * 32 + t];
    if (t == 0) rnn[16] = velocity[b];
    if (t == 1) rnn[17] = log_pitch[b];
    if (t == 2) rnn[18] = time_in[b];

    // chunk0: samples 0..1015 at half idx 16+s (write h4 = 8B aligned)
#pragma unroll
    for (int j = 0; j < 4; ++j) {
        int i = t + 64 * j;
        if (i < 254) {
            float4 q = row4[i];
            h4 hv = {(_Float16)q.x, (_Float16)q.y, (_Float16)q.z, (_Float16)q.w};
            *(h4*)(xbuf + 16 + 4 * i) = hv;
        }
    }
    __syncthreads();

    // ---------------- conv1 chunk 0: positions 0..249, h0 = 4p ----------
#pragma unroll
    for (int j = 0; j < 4; ++j) {
        int p = t + 64 * j;
        if (p < 250) conv1_pos(xbuf, y1h, w1p, b1, p, 4 * p);
    }
    __syncthreads();                     // WAR: all reads of xbuf done

    // ---------------- stage chunk 1: samples 984..1999 at idx 16+(s-984) --
#pragma unroll
    for (int j = 0; j < 4; ++j) {
        int i = t + 64 * j;
        if (i < 254) {
            float4 q = row4[246 + i];
            h4 hv = {(_Float16)q.x, (_Float16)q.y, (_Float16)q.z, (_Float16)q.w};
            *(h4*)(xbuf + 16 + 4 * i) = hv;
        }
    }
    __syncthreads();

    // ---------------- conv1 chunk 1: positions 250..499, h0 = 4p-984 ------
#pragma unroll
    for (int j = 0; j < 4; ++j) {
        int p = 250 + t + 64 * j;
        if (p < 500) conv1_pos(xbuf, y1h, w1p, b1, p, 4 * p - 984);
    }
    __syncthreads();                     // xbuf dead; X becomes y2h

    // ---------------- conv2: 4->8ch, k=15, s=4 (+ y2h pad zeroing) --------
    if (t < 56) { int c = t / 7, k = t % 7;
                  y2h[c * 132 + (k < 3 ? k : 125 + k)] = (_Float16)0.0f; }
#pragma unroll
    for (int jj = 0; jj < 2; ++jj) {
        int p = t + 64 * jj;
        if (p < 125) {
            float acc[8];
#pragma unroll
            for (int c = 0; c < 8; ++c) acc[c] = b2[c];
#pragma unroll
            for (int ci = 0; ci < 4; ++ci) {
                // window = stored halfs [4p .. 4p+15] (taps 0..14 + pad)
                const h4* src = (const h4*)(y1h + 512 * ci + 4 * p);
                h2 xp[8];
#pragma unroll
                for (int j = 0; j < 4; ++j) {
                    h4 v = src[j];
                    xp[2 * j]     = (h2){v.x, v.y};
                    xp[2 * j + 1] = (h2){v.z, v.w};
                }
#pragma unroll
                for (int jp = 0; jp < 8; ++jp) {
#pragma unroll
                    for (int c = 0; c < 8; ++c)
                        acc[c] = fdot2(xp[jp], w2p[(c * 4 + ci) * 8 + jp], acc[c]);
                }
            }
#pragma unroll
            for (int c = 0; c < 8; ++c)
                y2h[c * 132 + 3 + p] = (_Float16)fmaxf(acc[c], 0.0f);
        }
    }
    __syncthreads();

    // ------- conv3: 8->16ch, k=7, s=4 + relu + mean (lanes 0..31) ----------
    if (t < 32) {
        float acc[16];
#pragma unroll
        for (int c = 0; c < 16; ++c) acc[c] = 0.0f;
#pragma unroll
        for (int ci = 0; ci < 8; ++ci) {
            // window = stored halfs [4t .. 4t+7] (taps 0..6 + pad)
            const h4* src = (const h4*)(y2h + 132 * ci + 4 * t);
            h4 v0 = src[0], v1 = src[1];
            h2 xp[4] = {(h2){v0.x, v0.y}, (h2){v0.z, v0.w},
                        (h2){v1.x, v1.y}, (h2){v1.z, v1.w}};
#pragma unroll
            for (int jp = 0; jp < 4; ++jp) {
#pragma unroll
                for (int c = 0; c < 16; ++c)
                    acc[c] = fdot2(xp[jp], w3p[(c * 8 + ci) * 4 + jp], acc[c]);
            }
        }
#pragma unroll
        for (int c = 0; c < 16; ++c) {
            float v = fmaxf(acc[c] + b3[c], 0.0f);
            v += __shfl_xor(v, 16); v += __shfl_xor(v, 8);
            v += __shfl_xor(v, 4);  v += __shfl_xor(v, 2);
            v += __shfl_xor(v, 1);
            if (t == 0) rnn[c] = v * (1.0f / 32.0f);
        }
    }
    __syncthreads();                    // y2h dead; X becomes gis|ghs

    // ---------------- GRU gates (round-2 structure, LDS-based) -------------
    {
        float rv[19];
#pragma unroll
        for (int j = 0; j < 19; ++j) rv[j] = rnn[j];

        float a = b_ih[t];
        const float* wr = w_ih + t * 19;
#pragma unroll
        for (int j = 0; j < 19; ++j) a += rv[j] * wr[j];
        gis[t] = a;
        if (t < 32) {
            float a2 = b_ih[64 + t];
            const float* wr2 = w_ih + (64 + t) * 19;
#pragma unroll
            for (int j = 0; j < 19; ++j) a2 += rv[j] * wr2[j];
            gis[64 + t] = a2;
        }

        float hv[32];
#pragma unroll
        for (int j = 0; j < 32; ++j) hv[j] = hs[j];

        float g = b_hh[t];
        const float4* wh = (const float4*)(w_hh + t * 32);
#pragma unroll
        for (int j = 0; j < 8; ++j) {
            float4 q = wh[j];
            g += hv[4 * j] * q.x + hv[4 * j + 1] * q.y +
                 hv[4 * j + 2] * q.z + hv[4 * j + 3] * q.w;
        }
        ghs[t] = g;
        if (t < 32) {
            float g2 = b_hh[64 + t];
            const float4* wh2 = (const float4*)(w_hh + (64 + t) * 32);
#pragma unroll
            for (int j = 0; j < 8; ++j) {
                float4 q = wh2[j];
                g2 += hv[4 * j] * q.x + hv[4 * j + 1] * q.y +
                      hv[4 * j + 2] * q.z + hv[4 * j + 3] * q.w;
            }
            ghs[64 + t] = g2;
        }
    }
    __syncthreads();

    // ---------------- combine + projection (lanes 0..31) ----------------
    if (t < 32) {
        const int j = t;
        float r = 1.0f / (1.0f + expf(-(gis[j] + ghs[j])));
        float z = 1.0f / (1.0f + expf(-(gis[32 + j] + ghs[32 + j])));
        float n = tanhf(gis[64 + j] + r * ghs[64 + j]);
        float nh = (1.0f - z) * n + z * hs[j];
        out[(size_t)2 * B + (size_t)b * 32 + j] = nh;   // new_hidden

        float p0 = nh * w_proj[j];
        float p1 = nh * w_proj[32 + j];
        p0 += __shfl_xor(p0, 16); p1 += __shfl_xor(p1, 16);
        p0 += __shfl_xor(p0, 8);  p1 += __shfl_xor(p1, 8);
        p0 += __shfl_xor(p0, 4);  p1 += __shfl_xor(p1, 4);
        p0 += __shfl_xor(p0, 2);  p1 += __shfl_xor(p1, 2);
        p0 += __shfl_xor(p0, 1);  p1 += __shfl_xor(p1, 1);
        if (j == 0) {
            out[b] = p0 + b_proj[0];                    // mu
            out[B + b] = expf(p1 + b_proj[1]);          // sigma
        }
    }
}

extern "C" void kernel_launch(void* const* d_in, const int* in_sizes, int n_in,
                              void* d_out, int out_size, void* d_ws, size_t ws_size,
                              hipStream_t stream)
{
    const float* past      = (const float*)d_in[0];
    const float* velocity  = (const float*)d_in[1];
    const float* log_pitch = (const float*)d_in[2];
    const float* time_in   = (const float*)d_in[3];
    const float* hidden    = (const float*)d_in[4];
    const float* w1  = (const float*)d_in[5];
    const float* b1  = (const float*)d_in[6];
    const float* w2  = (const float*)d_in[7];
    const float* b2  = (const float*)d_in[8];
    const float* w3  = (const float*)d_in[9];
    const float* b3  = (const float*)d_in[10];
    const float* wih = (const float*)d_in[11];
    const float* whh = (const float*)d_in[12];
    const float* bih = (const float*)d_in[13];
    const float* bhh = (const float*)d_in[14];
    const float* wpr = (const float*)d_in[15];
    const float* bpr = (const float*)d_in[16];

    const int B = in_sizes[0] / 2000;
    h2* wsp = (h2*)d_ws;

    pack_weights<<<dim3(1), dim3(256), 0, stream>>>(w1, w2, w3, wsp);

    wavernn_fused<<<dim3(B), dim3(64), 0, stream>>>(
        past, velocity, log_pitch, time_in, hidden,
        b1, b2, b3, wih, whh, bih, bhh, wpr, bpr,
        (const h2*)wsp, (float*)d_out, B);
}